// Round 1
// baseline (292.159 us; speedup 1.0000x reference)
//
#include <hip/hip_runtime.h>
#include <cstdint>

typedef __bf16 bf16_t;
typedef bf16_t bf16x8 __attribute__((ext_vector_type(8)));
typedef float f32x4 __attribute__((ext_vector_type(4)));

#define GLD_LDS16(g, l)                                                        \
  __builtin_amdgcn_global_load_lds(                                            \
      (const __attribute__((address_space(1))) void*)(g),                      \
      (__attribute__((address_space(3))) void*)(l), 16, 0, 0)

static __device__ __forceinline__ unsigned short bf16_bits(float f) {
  bf16_t h = (bf16_t)f;
  return __builtin_bit_cast(unsigned short, h);
}

// ---------------- fp32 -> bf16 elementwise convert (8 elems/thread) --------
__global__ void cvt_kernel(const float* __restrict__ src,
                           bf16_t* __restrict__ dst, int n8) {
  int i = blockIdx.x * blockDim.x + threadIdx.x;
  if (i >= n8) return;
  const float4* s = (const float4*)src;
  float4 a = s[i * 2];
  float4 b = s[i * 2 + 1];
  bf16x8 o;
  o[0] = (bf16_t)a.x; o[1] = (bf16_t)a.y; o[2] = (bf16_t)a.z; o[3] = (bf16_t)a.w;
  o[4] = (bf16_t)b.x; o[5] = (bf16_t)b.y; o[6] = (bf16_t)b.z; o[7] = (bf16_t)b.w;
  *(bf16x8*)(dst + (size_t)i * 8) = o;
}

// ---------------- fp32 [R][C] -> bf16 [C][R] transpose-convert -------------
__global__ void tcvt_kernel(const float* __restrict__ src,
                            bf16_t* __restrict__ dst, int R, int C) {
  __shared__ float tile[32][33];
  int r0 = blockIdx.y << 5, c0 = blockIdx.x << 5;
  int tc = threadIdx.x & 31, tr = threadIdx.x >> 5;  // tr in 0..7
#pragma unroll
  for (int i = 0; i < 4; i++)
    tile[tr + i * 8][tc] = src[(size_t)(r0 + tr + i * 8) * C + c0 + tc];
  __syncthreads();
#pragma unroll
  for (int i = 0; i < 4; i++)
    dst[(size_t)(c0 + tr + i * 8) * R + r0 + tc] = (bf16_t)tile[tc][tr + i * 8];
}

// ---------------- 128x128x32 bf16 GEMM, C = A * BT^T (both K-inner) --------
// MODE 0: bf16 C[m][n] (scaled); MODE 1: bf16 C^T[n][m]; MODE 2: fp32 C[m][n]
template <int MODE>
__global__ __launch_bounds__(256, 2) void gemm_bt(
    const bf16_t* __restrict__ A0, const bf16_t* __restrict__ A1, int lda,
    int Ksplit, const bf16_t* __restrict__ BT, int Ktot,
    void* __restrict__ Cp, int ldc, float scale) {
  __shared__ bf16_t As[128 * 32];
  __shared__ bf16_t Bs[128 * 32];
  const int t = threadIdx.x, w = t >> 6, l = t & 63;
  const int l15 = l & 15, l4 = l >> 4;
  const int wr = w >> 1, wc = w & 1;
  const int m0 = blockIdx.y * 128, n0 = blockIdx.x * 128;
  f32x4 acc[4][4] = {};
  const int nkt = Ktot >> 5;
  const int ch0 = (w * 2) * 64 + l, ch1 = ch0 + 64;
  const int arow0 = ch0 >> 2, akk0 = (ch0 & 3) * 8;
  const int arow1 = ch1 >> 2, akk1 = (ch1 & 3) * 8;

  for (int kt = 0; kt < nkt; ++kt) {
    const int kbase = kt * 32;
    {
      int kg0 = kbase + akk0;
      const bf16_t* s0 = (kg0 < Ksplit)
                             ? (A0 + (size_t)(m0 + arow0) * lda + kg0)
                             : (A1 + (size_t)(m0 + arow0) * lda + (kg0 - Ksplit));
      GLD_LDS16(s0, As + ch0 * 8);
      int kg1 = kbase + akk1;
      const bf16_t* s1 = (kg1 < Ksplit)
                             ? (A0 + (size_t)(m0 + arow1) * lda + kg1)
                             : (A1 + (size_t)(m0 + arow1) * lda + (kg1 - Ksplit));
      GLD_LDS16(s1, As + ch1 * 8);
      const bf16_t* b0 = BT + (size_t)(n0 + arow0) * Ktot + kbase + akk0;
      GLD_LDS16(b0, Bs + ch0 * 8);
      const bf16_t* b1 = BT + (size_t)(n0 + arow1) * Ktot + kbase + akk1;
      GLD_LDS16(b1, Bs + ch1 * 8);
    }
    __syncthreads();
    bf16x8 af[4], bfr[4];
#pragma unroll
    for (int mi = 0; mi < 4; mi++)
      af[mi] = *(const bf16x8*)&As[(wr * 64 + mi * 16 + l15) * 32 + l4 * 8];
#pragma unroll
    for (int ni = 0; ni < 4; ni++)
      bfr[ni] = *(const bf16x8*)&Bs[(wc * 64 + ni * 16 + l15) * 32 + l4 * 8];
#pragma unroll
    for (int mi = 0; mi < 4; mi++)
#pragma unroll
      for (int ni = 0; ni < 4; ni++)
        acc[mi][ni] = __builtin_amdgcn_mfma_f32_16x16x32_bf16(
            af[mi], bfr[ni], acc[mi][ni], 0, 0, 0);
    __syncthreads();
  }

#pragma unroll
  for (int mi = 0; mi < 4; mi++) {
#pragma unroll
    for (int ni = 0; ni < 4; ni++) {
      const int rbase = m0 + wr * 64 + mi * 16 + l4 * 4;
      const int col = n0 + wc * 64 + ni * 16 + l15;
      if (MODE == 0) {
        bf16_t* C = (bf16_t*)Cp;
#pragma unroll
        for (int rr = 0; rr < 4; rr++)
          C[(size_t)(rbase + rr) * ldc + col] =
              (bf16_t)(acc[mi][ni][rr] * scale);
      } else if (MODE == 1) {
        bf16_t* C = (bf16_t*)Cp;  // C^T [N][ldc]
        union { unsigned short u[4]; uint2 v; } pk;
#pragma unroll
        for (int rr = 0; rr < 4; rr++)
          pk.u[rr] = bf16_bits(acc[mi][ni][rr] * scale);
        *(uint2*)&C[(size_t)col * ldc + rbase] = pk.v;
      } else {
        float* C = (float*)Cp;
#pragma unroll
        for (int rr = 0; rr < 4; rr++)
          C[(size_t)(rbase + rr) * ldc + col] = acc[mi][ni][rr];
      }
    }
  }
}

// ---------------- flash attention: 64 head-batches, Lq=Lk=1024, d=64 -------
// grid (8 qtiles, 64 bh), 256 threads. logits = Q*K^T + 2*bias[b][k].
__global__ __launch_bounds__(256, 2) void attn_kernel(
    const bf16_t* __restrict__ Q, const bf16_t* __restrict__ K,
    const bf16_t* __restrict__ VT, const float* __restrict__ bias,
    bf16_t* __restrict__ ctx) {
  __shared__ bf16_t Ks[128 * 64];
  __shared__ bf16_t Vs[64 * 128];
  __shared__ bf16_t Ps[128 * 128];
  const int t = threadIdx.x, w = t >> 6, l = t & 63;
  const int l15 = l & 15, l4 = l >> 4;
  const int qt = blockIdx.x, bh = blockIdx.y;
  const int b = bh >> 4, h = bh & 15;
  const int qrow0 = b * 1024 + qt * 128;

  // Q fragments direct from global (bf16, K-inner): rows w*32+mi*16+l15
  bf16x8 qf[2][2];
  const bf16_t* Qb = Q + (size_t)(qrow0 + w * 32) * 1024 + h * 64;
#pragma unroll
  for (int mi = 0; mi < 2; mi++)
#pragma unroll
    for (int ks = 0; ks < 2; ks++)
      qf[mi][ks] =
          *(const bf16x8*)&Qb[(size_t)(mi * 16 + l15) * 1024 + ks * 32 + l4 * 8];

  float mrun[2][4], lrun[2][4];
  f32x4 ctxacc[2][4] = {};
#pragma unroll
  for (int mi = 0; mi < 2; mi++)
#pragma unroll
    for (int rr = 0; rr < 4; rr++) { mrun[mi][rr] = -INFINITY; lrun[mi][rr] = 0.f; }

  for (int kt = 0; kt < 8; ++kt) {
    // stage K tile [128 keys][64 d], XOR-swizzled via pre-swizzled global src
#pragma unroll
    for (int j = 0; j < 4; j++) {
      int c = (w * 4 + j) * 64 + l;
      int row = c >> 3;
      int slot = (c & 7) ^ (row & 7);
      const bf16_t* src =
          K + (size_t)(b * 1024 + kt * 128 + row) * 1024 + h * 64 + slot * 8;
      GLD_LDS16(src, Ks + c * 8);
    }
    // stage V^T tile [64 d][128 keys], swizzled
#pragma unroll
    for (int j = 0; j < 4; j++) {
      int c = (w * 4 + j) * 64 + l;
      int row = c >> 4;
      int slot = (c & 15) ^ (row & 7);
      const bf16_t* src =
          VT + (size_t)(h * 64 + row) * 4096 + b * 1024 + kt * 128 + slot * 8;
      GLD_LDS16(src, Vs + c * 8);
    }
    __syncthreads();

    // QK^T: each wave owns 32 q-rows x 128 keys
    f32x4 sacc[2][8] = {};
#pragma unroll
    for (int ks = 0; ks < 2; ks++) {
#pragma unroll
      for (int ni = 0; ni < 8; ni++) {
        int krow = ni * 16 + l15;
        int eoff = (krow * 64 + ks * 32 + l4 * 8) ^ ((krow & 7) << 3);
        bf16x8 kf = *(const bf16x8*)&Ks[eoff];
#pragma unroll
        for (int mi = 0; mi < 2; mi++)
          sacc[mi][ni] = __builtin_amdgcn_mfma_f32_16x16x32_bf16(
              qf[mi][ks], kf, sacc[mi][ni], 0, 0, 0);
      }
    }
    // + 2*bias (per key column)
#pragma unroll
    for (int ni = 0; ni < 8; ni++) {
      float bb = 2.0f * bias[b * 1024 + kt * 128 + ni * 16 + l15];
#pragma unroll
      for (int mi = 0; mi < 2; mi++)
#pragma unroll
        for (int rr = 0; rr < 4; rr++) sacc[mi][ni][rr] += bb;
    }
    // online softmax per q-row; write P (bf16, swizzled) to LDS
#pragma unroll
    for (int mi = 0; mi < 2; mi++) {
#pragma unroll
      for (int rr = 0; rr < 4; rr++) {
        float tm = sacc[mi][0][rr];
#pragma unroll
        for (int ni = 1; ni < 8; ni++) tm = fmaxf(tm, sacc[mi][ni][rr]);
        tm = fmaxf(tm, __shfl_xor(tm, 1));
        tm = fmaxf(tm, __shfl_xor(tm, 2));
        tm = fmaxf(tm, __shfl_xor(tm, 4));
        tm = fmaxf(tm, __shfl_xor(tm, 8));
        float mnew = fmaxf(mrun[mi][rr], tm);
        float sc = __expf(mrun[mi][rr] - mnew);
        float rsum = 0.f;
        int q = w * 32 + mi * 16 + l4 * 4 + rr;
#pragma unroll
        for (int ni = 0; ni < 8; ni++) {
          float p = __expf(sacc[mi][ni][rr] - mnew);
          rsum += p;
          int col = ni * 16 + l15;
          int eoff = (q * 128 + col) ^ ((q & 7) << 3);
          Ps[eoff] = (bf16_t)p;
        }
        rsum += __shfl_xor(rsum, 1);
        rsum += __shfl_xor(rsum, 2);
        rsum += __shfl_xor(rsum, 4);
        rsum += __shfl_xor(rsum, 8);
        lrun[mi][rr] = lrun[mi][rr] * sc + rsum;
        mrun[mi][rr] = mnew;
#pragma unroll
        for (int ni = 0; ni < 4; ni++) ctxacc[mi][ni][rr] *= sc;
      }
    }
    __syncthreads();
    // PV: ctx[q][dd] += P[q][k] * V[k][dd]
#pragma unroll
    for (int kk = 0; kk < 4; kk++) {
      bf16x8 pf[2], vf[4];
#pragma unroll
      for (int mi = 0; mi < 2; mi++) {
        int q = w * 32 + mi * 16 + l15;
        int eoff = (q * 128 + kk * 32 + l4 * 8) ^ ((q & 7) << 3);
        pf[mi] = *(const bf16x8*)&Ps[eoff];
      }
#pragma unroll
      for (int ni = 0; ni < 4; ni++) {
        int dd = ni * 16 + l15;
        int eoff = (dd * 128 + kk * 32 + l4 * 8) ^ ((dd & 7) << 3);
        vf[ni] = *(const bf16x8*)&Vs[eoff];
      }
#pragma unroll
      for (int mi = 0; mi < 2; mi++)
#pragma unroll
        for (int ni = 0; ni < 4; ni++)
          ctxacc[mi][ni] = __builtin_amdgcn_mfma_f32_16x16x32_bf16(
              pf[mi], vf[ni], ctxacc[mi][ni], 0, 0, 0);
    }
    __syncthreads();
  }
  // epilogue: ctx / l  -> bf16 [4096][1024]
#pragma unroll
  for (int mi = 0; mi < 2; mi++) {
#pragma unroll
    for (int rr = 0; rr < 4; rr++) {
      float inv = 1.0f / lrun[mi][rr];
      int qg = qrow0 + w * 32 + mi * 16 + l4 * 4 + rr;
#pragma unroll
      for (int ni = 0; ni < 4; ni++) {
        int col = h * 64 + ni * 16 + l15;
        ctx[(size_t)qg * 1024 + col] = (bf16_t)(ctxacc[mi][ni][rr] * inv);
      }
    }
  }
}

extern "C" void kernel_launch(void* const* d_in, const int* in_sizes, int n_in,
                              void* d_out, int out_size, void* d_ws,
                              size_t ws_size, hipStream_t stream) {
  const float* x = (const float*)d_in[0];    // [4,1024,1024]
  const float* y = (const float*)d_in[1];    // [2,4,1024,1024]
  const float* bias = (const float*)d_in[2]; // [4,1,1,1024]
  const float* Wq = (const float*)d_in[3];   // [1024,1024]
  const float* Wk = (const float*)d_in[4];   // [2,1024,1024] == [2048,1024]
  const float* Wv = (const float*)d_in[5];
  const float* Wo = (const float*)d_in[6];
  float* out = (float*)d_out;                // [4,1024,1024] fp32

  char* ws = (char*)d_ws;
  const size_t MB = 1024 * 1024;
  bf16_t* xb   = (bf16_t*)(ws + 0 * MB);    // 8MB
  bf16_t* yb   = (bf16_t*)(ws + 8 * MB);    // 16MB
  bf16_t* WqT  = (bf16_t*)(ws + 24 * MB);   // 2MB
  bf16_t* WkT  = (bf16_t*)(ws + 26 * MB);   // 4MB
  bf16_t* WvT  = (bf16_t*)(ws + 30 * MB);   // 4MB
  bf16_t* WoT  = (bf16_t*)(ws + 34 * MB);   // 2MB
  bf16_t* Qb   = (bf16_t*)(ws + 36 * MB);   // 8MB
  bf16_t* Kb   = (bf16_t*)(ws + 44 * MB);   // 8MB
  bf16_t* VTb  = (bf16_t*)(ws + 52 * MB);   // 8MB  (transposed: [1024][4096])
  bf16_t* ctxb = (bf16_t*)(ws + 60 * MB);   // 8MB

  cvt_kernel<<<2048, 256, 0, stream>>>(x, xb, 4 * 1024 * 1024 / 8);
  cvt_kernel<<<4096, 256, 0, stream>>>(y, yb, 8 * 1024 * 1024 / 8);
  tcvt_kernel<<<dim3(32, 32), 256, 0, stream>>>(Wq, WqT, 1024, 1024);
  tcvt_kernel<<<dim3(32, 64), 256, 0, stream>>>(Wk, WkT, 2048, 1024);
  tcvt_kernel<<<dim3(32, 64), 256, 0, stream>>>(Wv, WvT, 2048, 1024);
  tcvt_kernel<<<dim3(32, 32), 256, 0, stream>>>(Wo, WoT, 1024, 1024);

  // Q = (x Wq) * d^-0.5          [4096,1024]
  gemm_bt<0><<<dim3(8, 32), 256, 0, stream>>>(xb, xb, 1024, 1024, WqT, 1024,
                                              Qb, 1024, 0.125f);
  // Ksum = sum_l y_l Wk_l        [4096,1024]  (K-dim 2048 split across links)
  gemm_bt<0><<<dim3(8, 32), 256, 0, stream>>>(yb, yb + (size_t)4096 * 1024,
                                              1024, 1024, WkT, 2048, Kb, 1024,
                                              1.0f);
  // Vsum^T                        [1024][4096]
  gemm_bt<1><<<dim3(8, 32), 256, 0, stream>>>(yb, yb + (size_t)4096 * 1024,
                                              1024, 1024, WvT, 2048, VTb, 4096,
                                              1.0f);
  // attention
  attn_kernel<<<dim3(8, 64), 256, 0, stream>>>(Qb, Kb, VTb, bias, ctxb);
  // out = ctx Wo  (fp32 out)
  gemm_bt<2><<<dim3(8, 32), 256, 0, stream>>>(ctxb, ctxb, 1024, 1024, WoT,
                                              1024, out, 1024, 1.0f);
}

// Round 2
// 210.433 us; speedup vs baseline: 1.3884x; 1.3884x over previous
//
#include <hip/hip_runtime.h>
#include <cstdint>

typedef __bf16 bf16_t;
typedef bf16_t bf16x8 __attribute__((ext_vector_type(8)));
typedef float f32x4 __attribute__((ext_vector_type(4)));

#define GLD_LDS16(g, l)                                                        \
  __builtin_amdgcn_global_load_lds(                                            \
      (const __attribute__((address_space(1))) void*)(g),                      \
      (__attribute__((address_space(3))) void*)(l), 16, 0, 0)

static __device__ __forceinline__ unsigned short bf16_bits(float f) {
  bf16_t h = (bf16_t)f;
  return __builtin_bit_cast(unsigned short, h);
}

// ---------------- fp32 -> bf16 elementwise convert (8 elems/thread) --------
__global__ void cvt_kernel(const float* __restrict__ src,
                           bf16_t* __restrict__ dst, int n8) {
  int i = blockIdx.x * blockDim.x + threadIdx.x;
  if (i >= n8) return;
  const float4* s = (const float4*)src;
  float4 a = s[i * 2];
  float4 b = s[i * 2 + 1];
  bf16x8 o;
  o[0] = (bf16_t)a.x; o[1] = (bf16_t)a.y; o[2] = (bf16_t)a.z; o[3] = (bf16_t)a.w;
  o[4] = (bf16_t)b.x; o[5] = (bf16_t)b.y; o[6] = (bf16_t)b.z; o[7] = (bf16_t)b.w;
  *(bf16x8*)(dst + (size_t)i * 8) = o;
}

// ---------------- fp32 [R][C] -> bf16 [C][R] transpose-convert -------------
__global__ void tcvt_kernel(const float* __restrict__ src,
                            bf16_t* __restrict__ dst, int R, int C) {
  __shared__ float tile[32][33];
  int r0 = blockIdx.y << 5, c0 = blockIdx.x << 5;
  int tc = threadIdx.x & 31, tr = threadIdx.x >> 5;  // tr in 0..7
#pragma unroll
  for (int i = 0; i < 4; i++)
    tile[tr + i * 8][tc] = src[(size_t)(r0 + tr + i * 8) * C + c0 + tc];
  __syncthreads();
#pragma unroll
  for (int i = 0; i < 4; i++)
    dst[(size_t)(c0 + tr + i * 8) * R + r0 + tc] = (bf16_t)tile[tc][tr + i * 8];
}

// ---------------- 128x64x32 bf16 GEMM, C = A * BT^T (both K-inner) ---------
// Double-buffered prefetch 2-phase. Grid: 512 linear blocks (16 n x 32 m),
// XCD-swizzled so blocks sharing a B-panel share an XCD's L2.
// MODE 0: bf16 C[m][n] (scaled); MODE 1: bf16 C^T[n][m]; MODE 2: fp32 C[m][n]
template <int MODE>
__global__ __launch_bounds__(256, 2) void gemm_bt(
    const bf16_t* __restrict__ A0, const bf16_t* __restrict__ A1, int lda,
    int Ksplit, const bf16_t* __restrict__ BT, int Ktot,
    void* __restrict__ Cp, int ldc, float scale) {
  __shared__ bf16_t As[2][128 * 32];
  __shared__ bf16_t Bs[2][64 * 32];
  const int t = threadIdx.x, w = t >> 6, l = t & 63;
  const int l15 = l & 15, l4 = l >> 4;
  const int wr = w >> 1, wc = w & 1;
  const int i = blockIdx.x;
  const int xb = (i & 7) | (((i >> 3) & 1) << 3);  // n-tile (0..15)
  const int yb = i >> 4;                           // m-tile (0..31)
  const int m0 = yb * 128, n0 = xb * 64;
  f32x4 acc[4][2] = {};
  const int nkt = Ktot >> 5;
  // stage chunk ids: c0,c1 -> A (512 chunks), c2 -> B (256 chunks)
  const int c0 = t, c1 = t + 256, c2 = t;  // c2 indexes B chunks directly
  const int ar0 = c0 >> 2, ak0 = (c0 & 3) * 8;
  const int ar1 = c1 >> 2, ak1 = (c1 & 3) * 8;
  const int br2 = c2 >> 2, bk2 = (c2 & 3) * 8;

#define GEMM_STAGE(buf, kt)                                                    \
  {                                                                            \
    const int kbase = (kt) * 32;                                               \
    int kg0 = kbase + ak0;                                                     \
    const bf16_t* s0 = (kg0 < Ksplit)                                          \
                           ? (A0 + (size_t)(m0 + ar0) * lda + kg0)             \
                           : (A1 + (size_t)(m0 + ar0) * lda + (kg0 - Ksplit)); \
    GLD_LDS16(s0, As[buf] + c0 * 8);                                           \
    int kg1 = kbase + ak1;                                                     \
    const bf16_t* s1 = (kg1 < Ksplit)                                          \
                           ? (A0 + (size_t)(m0 + ar1) * lda + kg1)             \
                           : (A1 + (size_t)(m0 + ar1) * lda + (kg1 - Ksplit)); \
    GLD_LDS16(s1, As[buf] + c1 * 8);                                           \
    const bf16_t* b0 = BT + (size_t)(n0 + br2) * Ktot + kbase + bk2;           \
    GLD_LDS16(b0, Bs[buf] + c2 * 8);                                           \
  }

  GEMM_STAGE(0, 0);
  __syncthreads();
  int cur = 0;
  for (int kt = 0; kt < nkt; ++kt) {
    if (kt + 1 < nkt) GEMM_STAGE(cur ^ 1, kt + 1);
    bf16x8 af[4], bfr[2];
#pragma unroll
    for (int mi = 0; mi < 4; mi++)
      af[mi] = *(const bf16x8*)&As[cur][(wr * 64 + mi * 16 + l15) * 32 + l4 * 8];
#pragma unroll
    for (int ni = 0; ni < 2; ni++)
      bfr[ni] = *(const bf16x8*)&Bs[cur][(wc * 32 + ni * 16 + l15) * 32 + l4 * 8];
#pragma unroll
    for (int mi = 0; mi < 4; mi++)
#pragma unroll
      for (int ni = 0; ni < 2; ni++)
        acc[mi][ni] = __builtin_amdgcn_mfma_f32_16x16x32_bf16(
            af[mi], bfr[ni], acc[mi][ni], 0, 0, 0);
    __syncthreads();
    cur ^= 1;
  }

#pragma unroll
  for (int mi = 0; mi < 4; mi++) {
#pragma unroll
    for (int ni = 0; ni < 2; ni++) {
      const int rbase = m0 + wr * 64 + mi * 16 + l4 * 4;
      const int col = n0 + wc * 32 + ni * 16 + l15;
      if (MODE == 0) {
        bf16_t* C = (bf16_t*)Cp;
#pragma unroll
        for (int rr = 0; rr < 4; rr++)
          C[(size_t)(rbase + rr) * ldc + col] =
              (bf16_t)(acc[mi][ni][rr] * scale);
      } else if (MODE == 1) {
        bf16_t* C = (bf16_t*)Cp;  // C^T [N][ldc]
        union { unsigned short u[4]; uint2 v; } pk;
#pragma unroll
        for (int rr = 0; rr < 4; rr++)
          pk.u[rr] = bf16_bits(acc[mi][ni][rr] * scale);
        *(uint2*)&C[(size_t)col * ldc + rbase] = pk.v;
      } else {
        float* C = (float*)Cp;
#pragma unroll
        for (int rr = 0; rr < 4; rr++)
          C[(size_t)(rbase + rr) * ldc + col] = acc[mi][ni][rr];
      }
    }
  }
#undef GEMM_STAGE
}

// ---------------- flash attention: 64 head-batches, Lq=Lk=1024, d=64 -------
// QB=64 (4 waves x 16 q-rows), KB=64, double-buffered swizzled K/V in LDS,
// per-wave P scratch (no cross-wave barrier), prefetch 2-phase.
// Grid 1024 linear blocks; bh = id&63 so the 16 q-tile blocks of one (b,h)
// share an XCD (id%8 invariant) -> K/V panels served from that XCD's L2.
__global__ __launch_bounds__(256, 4) void attn_kernel(
    const bf16_t* __restrict__ Q, const bf16_t* __restrict__ K,
    const bf16_t* __restrict__ VT, const float* __restrict__ bias,
    bf16_t* __restrict__ ctx) {
  __shared__ bf16_t Ks[2][64 * 64];
  __shared__ bf16_t Vs[2][64 * 64];
  __shared__ bf16_t Ps[4][16 * 64];
  const int t = threadIdx.x, w = t >> 6, l = t & 63;
  const int l15 = l & 15, l4 = l >> 4;
  const int id = blockIdx.x;
  const int bh = id & 63, qt = id >> 6;
  const int b = bh >> 4, h = bh & 15;

  // Q fragments direct from global: wave w owns q-rows qt*64 + w*16 + 0..15
  bf16x8 qf[2];
  {
    const bf16_t* Qb = Q + (size_t)(b * 1024 + qt * 64 + w * 16 + l15) * 1024 +
                       h * 64;
#pragma unroll
    for (int ks = 0; ks < 2; ks++)
      qf[ks] = *(const bf16x8*)&Qb[ks * 32 + l4 * 8];
  }

  // stage chunks: 512 chunks of 16B per K tile; thread covers c=t,t+256 for K
  // and same for V. row = c>>3, slot = (c&7)^(row&7) (XOR bank swizzle).
#define ATTN_STAGE(buf, kt)                                                    \
  {                                                                            \
    _Pragma("unroll") for (int j = 0; j < 2; j++) {                            \
      int c = t + j * 256;                                                     \
      int row = c >> 3, sl = (c & 7) ^ (row & 7);                              \
      const bf16_t* srck =                                                     \
          K + (size_t)(b * 1024 + (kt) * 64 + row) * 1024 + h * 64 + sl * 8;   \
      GLD_LDS16(srck, Ks[buf] + c * 8);                                        \
      const bf16_t* srcv =                                                     \
          VT + (size_t)(h * 64 + row) * 4096 + b * 1024 + (kt) * 64 + sl * 8;  \
      GLD_LDS16(srcv, Vs[buf] + c * 8);                                        \
    }                                                                          \
  }

  float mrun[4], lrun[4];
  f32x4 ctxacc[4] = {};
#pragma unroll
  for (int rr = 0; rr < 4; rr++) { mrun[rr] = -INFINITY; lrun[rr] = 0.f; }

  ATTN_STAGE(0, 0);
  __syncthreads();
  int cur = 0;
  for (int kt = 0; kt < 16; ++kt) {
    if (kt + 1 < 16) ATTN_STAGE(cur ^ 1, kt + 1);

    // QK^T: wave computes 16 q x 64 keys
    f32x4 sacc[4] = {};
#pragma unroll
    for (int ks = 0; ks < 2; ks++) {
#pragma unroll
      for (int ni = 0; ni < 4; ni++) {
        int krow = ni * 16 + l15;
        int eoff = (krow * 64 + ks * 32 + l4 * 8) ^ ((krow & 7) << 3);
        bf16x8 kf = *(const bf16x8*)&Ks[cur][eoff];
        sacc[ni] = __builtin_amdgcn_mfma_f32_16x16x32_bf16(qf[ks], kf,
                                                           sacc[ni], 0, 0, 0);
      }
    }
    // + 2*bias per key column
#pragma unroll
    for (int ni = 0; ni < 4; ni++) {
      float bb = 2.0f * bias[b * 1024 + kt * 64 + ni * 16 + l15];
#pragma unroll
      for (int rr = 0; rr < 4; rr++) sacc[ni][rr] += bb;
    }
    // online softmax (rows l4*4+rr), write P to per-wave LDS scratch
#pragma unroll
    for (int rr = 0; rr < 4; rr++) {
      float tm = fmaxf(fmaxf(sacc[0][rr], sacc[1][rr]),
                       fmaxf(sacc[2][rr], sacc[3][rr]));
      tm = fmaxf(tm, __shfl_xor(tm, 1));
      tm = fmaxf(tm, __shfl_xor(tm, 2));
      tm = fmaxf(tm, __shfl_xor(tm, 4));
      tm = fmaxf(tm, __shfl_xor(tm, 8));
      float mnew = fmaxf(mrun[rr], tm);
      float sc = __expf(mrun[rr] - mnew);
      float rsum = 0.f;
      int q = l4 * 4 + rr;
#pragma unroll
      for (int ni = 0; ni < 4; ni++) {
        float p = __expf(sacc[ni][rr] - mnew);
        rsum += p;
        int eoff = (q * 64 + ni * 16 + l15) ^ ((q & 7) << 3);
        Ps[w][eoff] = (bf16_t)p;
      }
      rsum += __shfl_xor(rsum, 1);
      rsum += __shfl_xor(rsum, 2);
      rsum += __shfl_xor(rsum, 4);
      rsum += __shfl_xor(rsum, 8);
      lrun[rr] = lrun[rr] * sc + rsum;
      mrun[rr] = mnew;
#pragma unroll
      for (int ni = 0; ni < 4; ni++) ctxacc[ni][rr] *= sc;
    }
    // PV (per-wave: P rows are this wave's own -> no barrier needed)
#pragma unroll
    for (int kk = 0; kk < 2; kk++) {
      int poff = (l15 * 64 + kk * 32 + l4 * 8) ^ ((l15 & 7) << 3);
      bf16x8 pf = *(const bf16x8*)&Ps[w][poff];
#pragma unroll
      for (int ni = 0; ni < 4; ni++) {
        int drow = ni * 16 + l15;
        int voff = (drow * 64 + kk * 32 + l4 * 8) ^ ((drow & 7) << 3);
        bf16x8 vf = *(const bf16x8*)&Vs[cur][voff];
        ctxacc[ni] = __builtin_amdgcn_mfma_f32_16x16x32_bf16(pf, vf, ctxacc[ni],
                                                             0, 0, 0);
      }
    }
    __syncthreads();
    cur ^= 1;
  }
  // epilogue: ctx / l -> bf16 [4096][1024]
#pragma unroll
  for (int rr = 0; rr < 4; rr++) {
    float inv = 1.0f / lrun[rr];
    int qg = b * 1024 + qt * 64 + w * 16 + l4 * 4 + rr;
#pragma unroll
    for (int ni = 0; ni < 4; ni++) {
      int col = h * 64 + ni * 16 + l15;
      ctx[(size_t)qg * 1024 + col] = (bf16_t)(ctxacc[ni][rr] * inv);
    }
  }
#undef ATTN_STAGE
}

extern "C" void kernel_launch(void* const* d_in, const int* in_sizes, int n_in,
                              void* d_out, int out_size, void* d_ws,
                              size_t ws_size, hipStream_t stream) {
  const float* x = (const float*)d_in[0];    // [4,1024,1024]
  const float* y = (const float*)d_in[1];    // [2,4,1024,1024]
  const float* bias = (const float*)d_in[2]; // [4,1,1,1024]
  const float* Wq = (const float*)d_in[3];   // [1024,1024]
  const float* Wk = (const float*)d_in[4];   // [2,1024,1024] == [2048,1024]
  const float* Wv = (const float*)d_in[5];
  const float* Wo = (const float*)d_in[6];
  float* out = (float*)d_out;                // [4,1024,1024] fp32

  char* ws = (char*)d_ws;
  const size_t MB = 1024 * 1024;
  bf16_t* xb   = (bf16_t*)(ws + 0 * MB);    // 8MB
  bf16_t* yb   = (bf16_t*)(ws + 8 * MB);    // 16MB
  bf16_t* WqT  = (bf16_t*)(ws + 24 * MB);   // 2MB
  bf16_t* WkT  = (bf16_t*)(ws + 26 * MB);   // 4MB
  bf16_t* WvT  = (bf16_t*)(ws + 30 * MB);   // 4MB
  bf16_t* WoT  = (bf16_t*)(ws + 34 * MB);   // 2MB
  bf16_t* Qb   = (bf16_t*)(ws + 36 * MB);   // 8MB
  bf16_t* Kb   = (bf16_t*)(ws + 44 * MB);   // 8MB
  bf16_t* VTb  = (bf16_t*)(ws + 52 * MB);   // 8MB  (transposed: [1024][4096])
  bf16_t* ctxb = (bf16_t*)(ws + 60 * MB);   // 8MB

  cvt_kernel<<<2048, 256, 0, stream>>>(x, xb, 4 * 1024 * 1024 / 8);
  cvt_kernel<<<4096, 256, 0, stream>>>(y, yb, 8 * 1024 * 1024 / 8);
  tcvt_kernel<<<dim3(32, 32), 256, 0, stream>>>(Wq, WqT, 1024, 1024);
  tcvt_kernel<<<dim3(32, 64), 256, 0, stream>>>(Wk, WkT, 2048, 1024);
  tcvt_kernel<<<dim3(32, 64), 256, 0, stream>>>(Wv, WvT, 2048, 1024);
  tcvt_kernel<<<dim3(32, 32), 256, 0, stream>>>(Wo, WoT, 1024, 1024);

  // Q = (x Wq) * d^-0.5          [4096,1024]
  gemm_bt<0><<<512, 256, 0, stream>>>(xb, xb, 1024, 1024, WqT, 1024,
                                      Qb, 1024, 0.125f);
  // Ksum = sum_l y_l Wk_l        [4096,1024]  (K-dim 2048 split across links)
  gemm_bt<0><<<512, 256, 0, stream>>>(yb, yb + (size_t)4096 * 1024, 1024, 1024,
                                      WkT, 2048, Kb, 1024, 1.0f);
  // Vsum^T                        [1024][4096]
  gemm_bt<1><<<512, 256, 0, stream>>>(yb, yb + (size_t)4096 * 1024, 1024, 1024,
                                      WvT, 2048, VTb, 4096, 1.0f);
  // attention
  attn_kernel<<<1024, 256, 0, stream>>>(Qb, Kb, VTb, bias, ctxb);
  // out = ctx Wo  (fp32 out)
  gemm_bt<2><<<512, 256, 0, stream>>>(ctxb, ctxb, 1024, 1024, WoT, 1024,
                                      out, 1024, 1.0f);
}

// Round 3
// 153.993 us; speedup vs baseline: 1.8972x; 1.3665x over previous
//
#include <hip/hip_runtime.h>
#include <cstdint>

typedef __bf16 bf16_t;
typedef bf16_t bf16x4 __attribute__((ext_vector_type(4)));
typedef bf16_t bf16x8 __attribute__((ext_vector_type(8)));
typedef float f32x4 __attribute__((ext_vector_type(4)));

#define GLD_LDS16(g, l)                                                        \
  __builtin_amdgcn_global_load_lds(                                            \
      (const __attribute__((address_space(1))) void*)(g),                      \
      (__attribute__((address_space(3))) void*)(l), 16, 0, 0)

#define LOG2E 1.44269504088896340736f

static __device__ __forceinline__ unsigned short bf16_bits(float f) {
  bf16_t h = (bf16_t)f;
  return __builtin_bit_cast(unsigned short, h);
}

// ---------------- fp32 -> bf16 convert, x and y fused ----------------------
__global__ void cvt_kernel(const float* __restrict__ x,
                           const float* __restrict__ y,
                           bf16_t* __restrict__ xb, bf16_t* __restrict__ yb) {
  int i = blockIdx.x * blockDim.x + threadIdx.x;
  const float* src;
  bf16_t* dst;
  if (i < 524288) { src = x; dst = xb; }
  else            { src = y; dst = yb; i -= 524288; }
  const float4* s = (const float4*)src;
  float4 a = s[i * 2];
  float4 b = s[i * 2 + 1];
  bf16x8 o;
  o[0] = (bf16_t)a.x; o[1] = (bf16_t)a.y; o[2] = (bf16_t)a.z; o[3] = (bf16_t)a.w;
  o[4] = (bf16_t)b.x; o[5] = (bf16_t)b.y; o[6] = (bf16_t)b.z; o[7] = (bf16_t)b.w;
  *(bf16x8*)(dst + (size_t)i * 8) = o;
}

// ---------------- fp32 [R][1024] -> bf16 [1024][R] transpose, 4 mats -------
__global__ void tcvt_kernel(const float* __restrict__ Wq,
                            const float* __restrict__ Wk,
                            const float* __restrict__ Wv,
                            const float* __restrict__ Wo,
                            bf16_t* __restrict__ WqT, bf16_t* __restrict__ WkvT,
                            bf16_t* __restrict__ WoT) {
  __shared__ float tile[32][33];
  int bid = blockIdx.x;
  const float* src; bf16_t* dst; int R, lb;
  if (bid < 1024)      { src = Wq; dst = WqT;          R = 1024; lb = bid; }
  else if (bid < 3072) { src = Wk; dst = WkvT;         R = 2048; lb = bid - 1024; }
  else if (bid < 5120) { src = Wv; dst = WkvT + (size_t)1024 * 2048; R = 2048; lb = bid - 3072; }
  else                 { src = Wo; dst = WoT;          R = 1024; lb = bid - 5120; }
  int c0 = (lb & 31) << 5, r0 = (lb >> 5) << 5;
  int tc = threadIdx.x & 31, tr = threadIdx.x >> 5;  // tr in 0..7
#pragma unroll
  for (int i = 0; i < 4; i++)
    tile[tr + i * 8][tc] = src[(size_t)(r0 + tr + i * 8) * 1024 + c0 + tc];
  __syncthreads();
#pragma unroll
  for (int i = 0; i < 4; i++)
    dst[(size_t)(c0 + tr + i * 8) * R + r0 + tc] = (bf16_t)tile[tc][tr + i * 8];
}

// ---------------- 128x64x32 bf16 GEMM, C = A * BT^T (both K-inner) ---------
// XCD swizzle: blocks sharing an A-panel (yb) live on one XCD -> A from HBM
// exactly once. MODE 0: bf16 C (scaled); MODE 2: fp32 C; MODE 3: KV-fused
// (xb<16 -> bf16 K to Cp; xb>=16 -> bf16 V^T to Cp2).
template <int MODE, int NXB>
__global__ __launch_bounds__(256, 2) void gemm_bt(
    const bf16_t* __restrict__ A0, const bf16_t* __restrict__ A1, int lda,
    int Ksplit, const bf16_t* __restrict__ BT, int Ktot,
    void* __restrict__ Cp, void* __restrict__ Cp2, int ldc, float scale) {
  __shared__ bf16_t As[2][128 * 32];
  __shared__ bf16_t Bs[2][64 * 32];
  const int t = threadIdx.x, w = t >> 6, l = t & 63;
  const int l15 = l & 15, l4 = l >> 4;
  const int wr = w >> 1, wc = w & 1;
  const int i = blockIdx.x;
  const int j = i >> 3;
  const int yb = (i & 7) * 4 + (j & 3);  // m-tile: 4 consecutive per XCD
  const int xb = j >> 2;                 // n-tile
  const int m0 = yb * 128, n0 = xb * 64;
  f32x4 acc[4][2] = {};
  const int nkt = Ktot >> 5;
  const int c0 = t, c1 = t + 256, c2 = t;
  const int ar0 = c0 >> 2, ak0 = (c0 & 3) * 8;
  const int ar1 = c1 >> 2, ak1 = (c1 & 3) * 8;
  const int br2 = c2 >> 2, bk2 = (c2 & 3) * 8;

#define GEMM_STAGE(buf, kt)                                                    \
  {                                                                            \
    const int kbase = (kt) * 32;                                               \
    int kg0 = kbase + ak0;                                                     \
    const bf16_t* s0 = (kg0 < Ksplit)                                          \
                           ? (A0 + (size_t)(m0 + ar0) * lda + kg0)             \
                           : (A1 + (size_t)(m0 + ar0) * lda + (kg0 - Ksplit)); \
    GLD_LDS16(s0, As[buf] + c0 * 8);                                           \
    int kg1 = kbase + ak1;                                                     \
    const bf16_t* s1 = (kg1 < Ksplit)                                          \
                           ? (A0 + (size_t)(m0 + ar1) * lda + kg1)             \
                           : (A1 + (size_t)(m0 + ar1) * lda + (kg1 - Ksplit)); \
    GLD_LDS16(s1, As[buf] + c1 * 8);                                           \
    const bf16_t* b0 = BT + (size_t)(n0 + br2) * Ktot + kbase + bk2;           \
    GLD_LDS16(b0, Bs[buf] + c2 * 8);                                           \
  }

  GEMM_STAGE(0, 0);
  __syncthreads();
  int cur = 0;
  for (int kt = 0; kt < nkt; ++kt) {
    if (kt + 1 < nkt) GEMM_STAGE(cur ^ 1, kt + 1);
    bf16x8 af[4], bfr[2];
#pragma unroll
    for (int mi = 0; mi < 4; mi++)
      af[mi] = *(const bf16x8*)&As[cur][(wr * 64 + mi * 16 + l15) * 32 + l4 * 8];
#pragma unroll
    for (int ni = 0; ni < 2; ni++)
      bfr[ni] = *(const bf16x8*)&Bs[cur][(wc * 32 + ni * 16 + l15) * 32 + l4 * 8];
#pragma unroll
    for (int mi = 0; mi < 4; mi++)
#pragma unroll
      for (int ni = 0; ni < 2; ni++)
        acc[mi][ni] = __builtin_amdgcn_mfma_f32_16x16x32_bf16(
            af[mi], bfr[ni], acc[mi][ni], 0, 0, 0);
    __syncthreads();
    cur ^= 1;
  }

#pragma unroll
  for (int mi = 0; mi < 4; mi++) {
#pragma unroll
    for (int ni = 0; ni < 2; ni++) {
      const int rbase = m0 + wr * 64 + mi * 16 + l4 * 4;
      const int col = n0 + wc * 32 + ni * 16 + l15;
      if (MODE == 0) {
        bf16_t* C = (bf16_t*)Cp;
#pragma unroll
        for (int rr = 0; rr < 4; rr++)
          C[(size_t)(rbase + rr) * ldc + col] =
              (bf16_t)(acc[mi][ni][rr] * scale);
      } else if (MODE == 2) {
        float* C = (float*)Cp;
#pragma unroll
        for (int rr = 0; rr < 4; rr++)
          C[(size_t)(rbase + rr) * ldc + col] = acc[mi][ni][rr];
      } else {  // MODE 3: K normal / V transposed
        if (col < 1024) {
          bf16_t* C = (bf16_t*)Cp;
#pragma unroll
          for (int rr = 0; rr < 4; rr++)
            C[(size_t)(rbase + rr) * ldc + col] = (bf16_t)acc[mi][ni][rr];
        } else {
          bf16_t* VT = (bf16_t*)Cp2;
          union { unsigned short u[4]; uint2 v; } pk;
#pragma unroll
          for (int rr = 0; rr < 4; rr++)
            pk.u[rr] = bf16_bits(acc[mi][ni][rr]);
          *(uint2*)&VT[(size_t)(col - 1024) * 4096 + rbase] = pk.v;
        }
      }
    }
  }
#undef GEMM_STAGE
}

// ---------------- flash attention, swapped-softmax --------------------------
// QB=64 (4 waves x 16 q), KB=64. S^T = mfma(K,Q): key-reduction is
// register-local (15 fmax + 2 shfl). P^T -> per-wave LDS [key_hi][q][key_lo],
// PV = mfma(V^T, P^T). exp2-domain (log2e pre-folded into Q and bias).
__global__ __launch_bounds__(256, 4) void attn_kernel(
    const bf16_t* __restrict__ Q, const bf16_t* __restrict__ K,
    const bf16_t* __restrict__ VT, const float* __restrict__ bias,
    bf16_t* __restrict__ ctx) {
  __shared__ bf16_t Ks[2][64 * 64];
  __shared__ bf16_t Vs[2][64 * 64];
  __shared__ bf16_t Ps[4][1024];  // per-wave P^T: [khi(8)][q(16)][klo(8)]
  const int t = threadIdx.x, w = t >> 6, l = t & 63;
  const int l15 = l & 15, l4 = l >> 4;
  const int id = blockIdx.x;
  const int bh = id & 63, qt = id >> 6;
  const int b = bh >> 4, h = bh & 15;

  // Q as B-operand: col=q=w*16+l15, inner d = ks*32+l4*8+j
  bf16x8 qf[2];
  {
    const bf16_t* Qb =
        Q + (size_t)(b * 1024 + qt * 64 + w * 16 + l15) * 1024 + h * 64;
#pragma unroll
    for (int ks = 0; ks < 2; ks++)
      qf[ks] = *(const bf16x8*)&Qb[ks * 32 + l4 * 8];
  }

#define ATTN_STAGE(buf, kt)                                                    \
  {                                                                            \
    _Pragma("unroll") for (int j = 0; j < 2; j++) {                            \
      int c = t + j * 256;                                                     \
      int row = c >> 3, sl = (c & 7) ^ (row & 7);                              \
      const bf16_t* srck =                                                     \
          K + (size_t)(b * 1024 + (kt) * 64 + row) * 1024 + h * 64 + sl * 8;   \
      GLD_LDS16(srck, Ks[buf] + c * 8);                                        \
      const bf16_t* srcv =                                                     \
          VT + (size_t)(h * 64 + row) * 4096 + b * 1024 + (kt) * 64 + sl * 8;  \
      GLD_LDS16(srcv, Vs[buf] + c * 8);                                        \
    }                                                                          \
  }

  float mrun = -INFINITY, lrun = 0.f;
  f32x4 ctxacc[4] = {};  // ctx^T: d=ni*16+l4*4+rr, q=w*16+l15

  ATTN_STAGE(0, 0);
  __syncthreads();
  int cur = 0;
  for (int kt = 0; kt < 16; ++kt) {
    if (kt + 1 < 16) ATTN_STAGE(cur ^ 1, kt + 1);

    // S^T: sacc[ni] holds keys ni*16+l4*4+rr for q=l15 (wave-local)
    f32x4 sacc[4] = {};
#pragma unroll
    for (int ks = 0; ks < 2; ks++) {
#pragma unroll
      for (int ni = 0; ni < 4; ni++) {
        int krow = ni * 16 + l15;
        int eoff = (krow * 64 + ks * 32 + l4 * 8) ^ ((krow & 7) << 3);
        bf16x8 kf = *(const bf16x8*)&Ks[cur][eoff];
        sacc[ni] = __builtin_amdgcn_mfma_f32_16x16x32_bf16(kf, qf[ks],
                                                           sacc[ni], 0, 0, 0);
      }
    }
    // + bias*2*log2e (per key = row of S^T): contiguous float4 per ni
#pragma unroll
    for (int ni = 0; ni < 4; ni++) {
      float4 bb =
          *(const float4*)&bias[b * 1024 + kt * 64 + ni * 16 + l4 * 4];
      sacc[ni][0] += (2.0f * LOG2E) * bb.x;
      sacc[ni][1] += (2.0f * LOG2E) * bb.y;
      sacc[ni][2] += (2.0f * LOG2E) * bb.z;
      sacc[ni][3] += (2.0f * LOG2E) * bb.w;
    }
    // softmax (base 2), register-local over 16 values + 2 shuffles
    float tm = -INFINITY;
#pragma unroll
    for (int ni = 0; ni < 4; ni++)
#pragma unroll
      for (int rr = 0; rr < 4; rr++) tm = fmaxf(tm, sacc[ni][rr]);
    tm = fmaxf(tm, __shfl_xor(tm, 16));
    tm = fmaxf(tm, __shfl_xor(tm, 32));
    float mnew = fmaxf(mrun, tm);
    float sc = exp2f(mrun - mnew);
    float rsum = 0.f;
#pragma unroll
    for (int ni = 0; ni < 4; ni++) {
      bf16x4 pk;
#pragma unroll
      for (int rr = 0; rr < 4; rr++) {
        float p = exp2f(sacc[ni][rr] - mnew);
        rsum += p;
        pk[rr] = (bf16_t)p;
      }
      // key = ni*16 + l4*4 + rr -> khi = ni*2+(l4>>1), klo = (l4&1)*4+rr
      *(bf16x4*)&Ps[w][(ni * 2 + (l4 >> 1)) * 128 + l15 * 8 + (l4 & 1) * 4] =
          pk;
    }
    rsum += __shfl_xor(rsum, 16);
    rsum += __shfl_xor(rsum, 32);
    lrun = lrun * sc + rsum;
    mrun = mnew;
#pragma unroll
    for (int ni = 0; ni < 4; ni++) ctxacc[ni] *= sc;
    // PV: ctx^T = mfma(A=V^T[d][key], B=P^T[key][q])
#pragma unroll
    for (int kk = 0; kk < 2; kk++) {
      bf16x8 pf = *(const bf16x8*)&Ps[w][(kk * 4 + l4) * 128 + l15 * 8];
#pragma unroll
      for (int ni = 0; ni < 4; ni++) {
        int drow = ni * 16 + l15;
        int voff = (drow * 64 + kk * 32 + l4 * 8) ^ ((drow & 7) << 3);
        bf16x8 vf = *(const bf16x8*)&Vs[cur][voff];
        ctxacc[ni] = __builtin_amdgcn_mfma_f32_16x16x32_bf16(vf, pf, ctxacc[ni],
                                                             0, 0, 0);
      }
    }
    __syncthreads();
    cur ^= 1;
  }

  // epilogue: ctx^T -> LDS transpose (swizzled) -> coalesced bf16x8 stores
  bf16_t* T = Ks[0];  // 64q x 64d
  {
    float inv = 1.0f / lrun;
    int q = w * 16 + l15;
#pragma unroll
    for (int ni = 0; ni < 4; ni++) {
      bf16x4 tv;
#pragma unroll
      for (int rr = 0; rr < 4; rr++) tv[rr] = (bf16_t)(ctxacc[ni][rr] * inv);
      int d0 = ni * 16 + l4 * 4;
      *(bf16x4*)&T[q * 64 + (d0 ^ ((l15 & 7) << 3))] = tv;
    }
  }
  __syncthreads();
#pragma unroll
  for (int c = t; c < 512; c += 256) {
    int row = c >> 3, col8 = c & 7;
    bf16x8 v = *(const bf16x8*)&T[row * 64 + ((col8 * 8) ^ ((row & 7) << 3))];
    *(bf16x8*)&ctx[(size_t)(b * 1024 + qt * 64 + row) * 1024 + h * 64 +
                   col8 * 8] = v;
  }
#undef ATTN_STAGE
}

extern "C" void kernel_launch(void* const* d_in, const int* in_sizes, int n_in,
                              void* d_out, int out_size, void* d_ws,
                              size_t ws_size, hipStream_t stream) {
  const float* x = (const float*)d_in[0];    // [4,1024,1024]
  const float* y = (const float*)d_in[1];    // [2,4,1024,1024]
  const float* bias = (const float*)d_in[2]; // [4,1,1,1024]
  const float* Wq = (const float*)d_in[3];   // [1024,1024]
  const float* Wk = (const float*)d_in[4];   // [2,1024,1024]
  const float* Wv = (const float*)d_in[5];
  const float* Wo = (const float*)d_in[6];
  float* out = (float*)d_out;                // [4,1024,1024] fp32

  char* ws = (char*)d_ws;
  const size_t MB = 1024 * 1024;
  bf16_t* xb   = (bf16_t*)(ws + 0 * MB);    // 8MB
  bf16_t* yb   = (bf16_t*)(ws + 8 * MB);    // 16MB
  bf16_t* WqT  = (bf16_t*)(ws + 24 * MB);   // 2MB
  bf16_t* WkvT = (bf16_t*)(ws + 26 * MB);   // 8MB  [2048 n][2048 k]
  bf16_t* WoT  = (bf16_t*)(ws + 34 * MB);   // 2MB
  bf16_t* Qb   = (bf16_t*)(ws + 36 * MB);   // 8MB  (pre-scaled by d^-.5*log2e)
  bf16_t* Kb   = (bf16_t*)(ws + 44 * MB);   // 8MB
  bf16_t* VTb  = (bf16_t*)(ws + 52 * MB);   // 8MB  [1024 d][4096 q]
  bf16_t* ctxb = (bf16_t*)(ws + 60 * MB);   // 8MB

  cvt_kernel<<<6144, 256, 0, stream>>>(x, y, xb, yb);
  tcvt_kernel<<<6144, 256, 0, stream>>>(Wq, Wk, Wv, Wo, WqT, WkvT, WoT);

  // Q = (x Wq) * d^-0.5 * log2e
  gemm_bt<0, 16><<<512, 256, 0, stream>>>(xb, xb, 1024, 1024, WqT, 1024, Qb,
                                          nullptr, 1024, 0.125f * LOG2E);
  // K = sum_l y_l Wk_l ; V^T = (sum_l y_l Wv_l)^T   (fused, N=2048)
  gemm_bt<3, 32><<<1024, 256, 0, stream>>>(yb, yb + (size_t)4096 * 1024, 1024,
                                           1024, WkvT, 2048, Kb, VTb, 1024,
                                           1.0f);
  attn_kernel<<<1024, 256, 0, stream>>>(Qb, Kb, VTb, bias, ctxb);
  // out = ctx Wo (fp32)
  gemm_bt<2, 16><<<512, 256, 0, stream>>>(ctxb, ctxb, 1024, 1024, WoT, 1024,
                                          out, nullptr, 1024, 1.0f);
}